// Round 5
// baseline (405.524 us; speedup 1.0000x reference)
//
#include <hip/hip_runtime.h>

#define NN 50000
#define NE 800000
#define D 128
#define GG 782            // gemm blocks (64 rows each): 782*64 = 50048
#define SCAN_BLOCKS 196   // ceil(50000/256)
#define XBLK 6250         // x conversion blocks (NN*D/4/256)
#define WBLK 96           // weight conversion blocks (6 * 16)
#define HBLK 3125         // histogram blocks (NE/256)
#define FBLK 3125         // fill blocks
#define LDS_STRIDE 136    // ushorts per LDS row: 128 + 8 pad (272 B)

typedef __attribute__((ext_vector_type(8))) short bf16x8;
typedef __attribute__((ext_vector_type(4))) float f32x4;

__device__ inline unsigned short f2bf(float f) {
    union { float f; unsigned u; } v; v.f = f;
    unsigned r = v.u + 0x7FFF + ((v.u >> 16) & 1);  // RNE
    return (unsigned short)(r >> 16);
}
__device__ inline float bf2f(unsigned b) {
    union { unsigned u; float f; } v; v.u = b << 16;
    return v.f;
}

// ---- fused: convert x + 6 weights to bf16, histogram dst degrees ----
__global__ __launch_bounds__(256)
void prep(const float* __restrict__ x,
          const float* __restrict__ w0, const float* __restrict__ w1,
          const float* __restrict__ w2, const float* __restrict__ w3,
          const float* __restrict__ w4, const float* __restrict__ w5,
          const int* __restrict__ ei,
          unsigned short* __restrict__ xb, unsigned short* __restrict__ wb,
          int* __restrict__ cnt) {
    const unsigned b = blockIdx.x;
    if (b < XBLK) {
        int i = b * 256 + threadIdx.x;
        float4 v = ((const float4*)x)[i];
        ushort4 o = {f2bf(v.x), f2bf(v.y), f2bf(v.z), f2bf(v.w)};
        ((ushort4*)xb)[i] = o;
    } else if (b < XBLK + WBLK) {
        const float* ws_[6] = {w0, w1, w2, w3, w4, w5};
        int wi = (int)(b - XBLK) >> 4;
        int off = ((int)(b - XBLK) & 15) * 256 + threadIdx.x;  // float4 idx
        float4 v = ((const float4*)ws_[wi])[off];
        ushort4 o = {f2bf(v.x), f2bf(v.y), f2bf(v.z), f2bf(v.w)};
        ((ushort4*)(wb + wi * D * D))[off] = o;
    } else {
        int e = (int)(b - XBLK - WBLK) * 256 + threadIdx.x;
        atomicAdd(&cnt[ei[NE + e]], 1);
    }
}

// ---------------- CSR scan chain ----------------
__global__ __launch_bounds__(256)
void scan_block(const int* __restrict__ cnt, int* __restrict__ row_start,
                int* __restrict__ bsum) {
    __shared__ int tmp[256];
    int i = blockIdx.x * 256 + threadIdx.x;
    int v = (i < NN) ? cnt[i] : 0;
    tmp[threadIdx.x] = v;
    __syncthreads();
    for (int off = 1; off < 256; off <<= 1) {
        int t = (threadIdx.x >= off) ? tmp[threadIdx.x - off] : 0;
        __syncthreads();
        tmp[threadIdx.x] += t;
        __syncthreads();
    }
    if (i < NN) row_start[i] = tmp[threadIdx.x] - v;  // exclusive
    if (threadIdx.x == 255) bsum[blockIdx.x] = tmp[255];
}

__global__ __launch_bounds__(256)
void scan_sums(int* __restrict__ bsum) {
    __shared__ int tmp[256];
    int v = (threadIdx.x < SCAN_BLOCKS) ? bsum[threadIdx.x] : 0;
    tmp[threadIdx.x] = v;
    __syncthreads();
    for (int off = 1; off < 256; off <<= 1) {
        int t = (threadIdx.x >= off) ? tmp[threadIdx.x - off] : 0;
        __syncthreads();
        tmp[threadIdx.x] += t;
        __syncthreads();
    }
    if (threadIdx.x < SCAN_BLOCKS) bsum[threadIdx.x] = tmp[threadIdx.x] - v;
}

__global__ __launch_bounds__(256)
void add_offsets(int* __restrict__ row_start, const int* __restrict__ bsum,
                 int* __restrict__ cursor) {
    int i = blockIdx.x * 256 + threadIdx.x;
    if (i < NN) {
        int v = row_start[i] + bsum[blockIdx.x];
        row_start[i] = v;
        cursor[i] = v;
    } else if (i == NN) {
        row_start[NN] = NE;
    }
}

// ---- fused: gemm (blocks [0,GG)) + CSR fill (blocks [GG,GG+FBLK)) ----
// gemm: out = relu(A@W.T + bias), 64 rows x 128 cols per block, no LDS.
__global__ __launch_bounds__(256)
void gemm_fill(const unsigned short* __restrict__ A,
               const unsigned short* __restrict__ W,
               const float* __restrict__ bias, unsigned short* __restrict__ outp,
               const int* __restrict__ ei, int* __restrict__ cursor,
               unsigned short* __restrict__ src16) {
    if (blockIdx.x >= GG) {
        int e = (int)(blockIdx.x - GG) * 256 + threadIdx.x;
        int src = ei[e];
        int dst = ei[NE + e];
        int pos = atomicAdd(&cursor[dst], 1);
        src16[pos] = (unsigned short)src;
        return;
    }
    const int lane = threadIdx.x & 63;
    const int wave = threadIdx.x >> 6;
    const int quad = lane >> 4;
    const int l16 = lane & 15;
    const int rowBase = blockIdx.x * 64 + wave * 16;

    f32x4 acc[8];
#pragma unroll
    for (int ni = 0; ni < 8; ++ni) acc[ni] = (f32x4){0.f, 0.f, 0.f, 0.f};

    int r = rowBase + l16;
    const int arow = (r < NN ? r : NN - 1) * D;

#pragma unroll
    for (int kt = 0; kt < 4; ++kt) {
        const int ko = kt * 32 + quad * 8;
        bf16x8 a0 = *(const bf16x8*)&A[arow + ko];
#pragma unroll
        for (int ni = 0; ni < 8; ++ni) {
            bf16x8 b = *(const bf16x8*)&W[(ni * 16 + l16) * D + ko];
            acc[ni] = __builtin_amdgcn_mfma_f32_16x16x32_bf16(a0, b, acc[ni], 0, 0, 0);
        }
    }

    float bv[8];
#pragma unroll
    for (int ni = 0; ni < 8; ++ni) bv[ni] = bias[ni * 16 + l16];

#pragma unroll
    for (int rr = 0; rr < 4; ++rr) {
        const int row = rowBase + quad * 4 + rr;
        if (row < NN) {
#pragma unroll
            for (int ni = 0; ni < 8; ++ni) {
                float v = acc[ni][rr] + bv[ni];
                v = v > 0.f ? v : 0.f;
                outp[row * D + (ni * 16 + l16)] = f2bf(v);
            }
        }
    }
}

// ---- plain gemm: out = relu(A@W.T + bias), bf16 out ----
__global__ __launch_bounds__(256)
void gemm_single(const unsigned short* __restrict__ A,
                 const unsigned short* __restrict__ W,
                 const float* __restrict__ bias,
                 unsigned short* __restrict__ outp) {
    const int lane = threadIdx.x & 63;
    const int wave = threadIdx.x >> 6;
    const int quad = lane >> 4;
    const int l16 = lane & 15;
    const int rowBase = blockIdx.x * 64 + wave * 16;

    f32x4 acc[8];
#pragma unroll
    for (int ni = 0; ni < 8; ++ni) acc[ni] = (f32x4){0.f, 0.f, 0.f, 0.f};

    int r = rowBase + l16;
    const int arow = (r < NN ? r : NN - 1) * D;

#pragma unroll
    for (int kt = 0; kt < 4; ++kt) {
        const int ko = kt * 32 + quad * 8;
        bf16x8 a0 = *(const bf16x8*)&A[arow + ko];
#pragma unroll
        for (int ni = 0; ni < 8; ++ni) {
            bf16x8 b = *(const bf16x8*)&W[(ni * 16 + l16) * D + ko];
            acc[ni] = __builtin_amdgcn_mfma_f32_16x16x32_bf16(a0, b, acc[ni], 0, 0, 0);
        }
    }

    float bv[8];
#pragma unroll
    for (int ni = 0; ni < 8; ++ni) bv[ni] = bias[ni * 16 + l16];

#pragma unroll
    for (int rr = 0; rr < 4; ++rr) {
        const int row = rowBase + quad * 4 + rr;
        if (row < NN) {
#pragma unroll
            for (int ni = 0; ni < 8; ++ni) {
                float v = acc[ni][rr] + bv[ni];
                v = v > 0.f ? v : 0.f;
                outp[row * D + (ni * 16 + l16)] = f2bf(v);
            }
        }
    }
}

// ---- fused combine: out = mean_agg(P)@Wl.T + X2@Wr.T + bias, opt relu ----
// Phase 1: gather-mean 64 rows into LDS (bf16, padded stride).
// Phase 2: dual MFMA, A1 from LDS, A2 from global.
template <typename OUTT>
__global__ __launch_bounds__(256)
void combine(const unsigned* __restrict__ P32, const int* __restrict__ row_start,
             const unsigned short* __restrict__ src16,
             const unsigned short* __restrict__ Wl,
             const unsigned short* __restrict__ X2,
             const unsigned short* __restrict__ Wr,
             const float* __restrict__ bias, OUTT* __restrict__ out,
             int do_relu) {
    __shared__ unsigned short aggLds[64 * LDS_STRIDE];
    const int lane = threadIdx.x & 63;
    const int wave = threadIdx.x >> 6;
    const int quad = lane >> 4;
    const int l16 = lane & 15;
    const int rowBase = blockIdx.x * 64;

    // phase 1: wave w gathers rows [rowBase+16w, +16)
    for (int rr = 0; rr < 16; ++rr) {
        const int rl = wave * 16 + rr;
        const int n = rowBase + rl;
        unsigned pk = 0;
        if (n < NN) {
            const int b = row_start[n];
            const int e = row_start[n + 1];
            float sx = 0.f, sy = 0.f;
            int i = b;
            for (; i + 8 <= e; i += 8) {
                int s0 = src16[i + 0], s1 = src16[i + 1];
                int s2 = src16[i + 2], s3 = src16[i + 3];
                int s4 = src16[i + 4], s5 = src16[i + 5];
                int s6 = src16[i + 6], s7 = src16[i + 7];
                unsigned u0 = P32[s0 * 64 + lane], u1 = P32[s1 * 64 + lane];
                unsigned u2 = P32[s2 * 64 + lane], u3 = P32[s3 * 64 + lane];
                unsigned u4 = P32[s4 * 64 + lane], u5 = P32[s5 * 64 + lane];
                unsigned u6 = P32[s6 * 64 + lane], u7 = P32[s7 * 64 + lane];
                sx += bf2f(u0 & 0xffffu) + bf2f(u1 & 0xffffu) +
                      bf2f(u2 & 0xffffu) + bf2f(u3 & 0xffffu) +
                      bf2f(u4 & 0xffffu) + bf2f(u5 & 0xffffu) +
                      bf2f(u6 & 0xffffu) + bf2f(u7 & 0xffffu);
                sy += bf2f(u0 >> 16) + bf2f(u1 >> 16) + bf2f(u2 >> 16) +
                      bf2f(u3 >> 16) + bf2f(u4 >> 16) + bf2f(u5 >> 16) +
                      bf2f(u6 >> 16) + bf2f(u7 >> 16);
            }
            for (; i < e; ++i) {
                unsigned u = P32[src16[i] * 64 + lane];
                sx += bf2f(u & 0xffffu);
                sy += bf2f(u >> 16);
            }
            const int deg = e - b;
            const float inv = 1.0f / (float)(deg > 0 ? deg : 1);
            pk = (unsigned)f2bf(sx * inv) | ((unsigned)f2bf(sy * inv) << 16);
        }
        *(unsigned*)&aggLds[rl * LDS_STRIDE + lane * 2] = pk;
    }
    __syncthreads();

    // phase 2: dual MFMA over 16 rows per wave
    f32x4 acc[8];
#pragma unroll
    for (int ni = 0; ni < 8; ++ni) acc[ni] = (f32x4){0.f, 0.f, 0.f, 0.f};

    const int rowW = rowBase + wave * 16;
    int r = rowW + l16;
    const int arow = (r < NN ? r : NN - 1) * D;
    const int ldsRow = (wave * 16 + l16) * LDS_STRIDE;

#pragma unroll
    for (int kt = 0; kt < 4; ++kt) {
        const int ko = kt * 32 + quad * 8;
        bf16x8 aL = *(const bf16x8*)&aggLds[ldsRow + ko];
        bf16x8 aX = *(const bf16x8*)&X2[arow + ko];
#pragma unroll
        for (int ni = 0; ni < 8; ++ni) {
            bf16x8 bL = *(const bf16x8*)&Wl[(ni * 16 + l16) * D + ko];
            bf16x8 bR = *(const bf16x8*)&Wr[(ni * 16 + l16) * D + ko];
            acc[ni] = __builtin_amdgcn_mfma_f32_16x16x32_bf16(aL, bL, acc[ni], 0, 0, 0);
            acc[ni] = __builtin_amdgcn_mfma_f32_16x16x32_bf16(aX, bR, acc[ni], 0, 0, 0);
        }
    }

    float bv[8];
#pragma unroll
    for (int ni = 0; ni < 8; ++ni) bv[ni] = bias[ni * 16 + l16];

#pragma unroll
    for (int rr = 0; rr < 4; ++rr) {
        const int row = rowW + quad * 4 + rr;
        if (row < NN) {
#pragma unroll
            for (int ni = 0; ni < 8; ++ni) {
                float v = acc[ni][rr] + bv[ni];
                if (do_relu) v = v > 0.f ? v : 0.f;
                const int c = ni * 16 + l16;
                if constexpr (sizeof(OUTT) == 2)
                    out[row * D + c] = (OUTT)f2bf(v);
                else
                    out[row * D + c] = (OUTT)v;
            }
        }
    }
}

extern "C" void kernel_launch(void* const* d_in, const int* in_sizes, int n_in,
                              void* d_out, int out_size, void* d_ws, size_t ws_size,
                              hipStream_t stream) {
    const float* x   = (const float*)d_in[0];
    const int*   ei  = (const int*)d_in[1];
    const float* Wp1 = (const float*)d_in[2];
    const float* bp1 = (const float*)d_in[3];
    const float* Wl1 = (const float*)d_in[4];
    const float* bl1 = (const float*)d_in[5];
    const float* Wr1 = (const float*)d_in[6];
    const float* Wp2 = (const float*)d_in[7];
    const float* bp2 = (const float*)d_in[8];
    const float* Wl2 = (const float*)d_in[9];
    const float* bl2 = (const float*)d_in[10];
    const float* Wr2 = (const float*)d_in[11];
    float* out = (float*)d_out;

    char* ws = (char*)d_ws;
    size_t off = 0;
    auto alloc = [&](size_t bytes) {
        void* p = ws + off;
        off += (bytes + 511) & ~511ull;
        return p;
    };
    unsigned short* Wb  = (unsigned short*)alloc((size_t)6 * D * D * 2);  // contiguous
    unsigned short* xb   = (unsigned short*)alloc((size_t)NN * D * 2);
    unsigned short* bufP = (unsigned short*)alloc((size_t)NN * D * 2);  // projected
    unsigned short* bufH = (unsigned short*)alloc((size_t)NN * D * 2);  // layer-1 out
    int* cnt        = (int*)alloc((size_t)NN * 4);
    int* row_start  = (int*)alloc((size_t)(NN + 1) * 4);
    int* cursor     = (int*)alloc((size_t)NN * 4);
    int* bsum       = (int*)alloc((size_t)SCAN_BLOCKS * 4);
    unsigned short* src16 = (unsigned short*)alloc((size_t)NE * 2);

    // 1. conversions + degree histogram (one dispatch)
    hipMemsetAsync(cnt, 0, (size_t)NN * 4, stream);
    prep<<<XBLK + WBLK + HBLK, 256, 0, stream>>>(
        x, Wp1, Wl1, Wr1, Wp2, Wl2, Wr2, ei, xb, Wb, cnt);

    // 2. scan chain
    scan_block<<<SCAN_BLOCKS, 256, 0, stream>>>(cnt, row_start, bsum);
    scan_sums<<<1, 256, 0, stream>>>(bsum);
    add_offsets<<<SCAN_BLOCKS, 256, 0, stream>>>(row_start, bsum, cursor);

    // 3. layer-1 projection gemm fused with CSR fill
    gemm_fill<<<GG + FBLK, 256, 0, stream>>>(
        xb, Wb + 0 * D * D, bp1, bufP, ei, cursor, src16);

    // 4. layer-1 combine: bufH = relu(agg@Wl1.T + x@Wr1.T + bl1)
    combine<unsigned short><<<GG, 256, 0, stream>>>(
        (const unsigned*)bufP, row_start, src16,
        Wb + 1 * D * D, xb, Wb + 2 * D * D, bl1, bufH, 1);

    // 5. layer-2 projection: bufP = relu(bufH@Wp2.T + bp2)
    gemm_single<<<GG, 256, 0, stream>>>(bufH, Wb + 3 * D * D, bp2, bufP);

    // 6. layer-2 combine: out = agg@Wl2.T + bufH@Wr2.T + bl2  (f32)
    combine<float><<<GG, 256, 0, stream>>>(
        (const unsigned*)bufP, row_start, src16,
        Wb + 4 * D * D, bufH, Wb + 5 * D * D, bl2, out, 0);
}

// Round 6
// 350.491 us; speedup vs baseline: 1.1570x; 1.1570x over previous
//
#include <hip/hip_runtime.h>

#define NN 50000
#define NE 800000
#define D 128
#define GG 782            // gemm blocks (64 rows each): 782*64 = 50048
#define SCAN_BLOCKS 196   // ceil(50000/256)
#define XBLK 6250         // x conversion blocks (NN*D/4/256)
#define WBLK 96           // weight conversion blocks (6 * 16)
#define HBLK 3125         // histogram blocks (NE/256)
#define FBLK 3125         // fill blocks

typedef __attribute__((ext_vector_type(8))) short bf16x8;
typedef __attribute__((ext_vector_type(4))) float f32x4;

__device__ inline unsigned short f2bf(float f) {
    union { float f; unsigned u; } v; v.f = f;
    unsigned r = v.u + 0x7FFF + ((v.u >> 16) & 1);  // RNE
    return (unsigned short)(r >> 16);
}
__device__ inline float bf2f(unsigned b) {
    union { unsigned u; float f; } v; v.u = b << 16;
    return v.f;
}

// ---- fused: convert x + 6 weights to bf16, histogram dst degrees ----
__global__ __launch_bounds__(256)
void prep(const float* __restrict__ x,
          const float* __restrict__ w0, const float* __restrict__ w1,
          const float* __restrict__ w2, const float* __restrict__ w3,
          const float* __restrict__ w4, const float* __restrict__ w5,
          const int* __restrict__ ei,
          unsigned short* __restrict__ xb, unsigned short* __restrict__ wb,
          int* __restrict__ cnt) {
    const unsigned b = blockIdx.x;
    if (b < XBLK) {
        int i = b * 256 + threadIdx.x;
        float4 v = ((const float4*)x)[i];
        ushort4 o = {f2bf(v.x), f2bf(v.y), f2bf(v.z), f2bf(v.w)};
        ((ushort4*)xb)[i] = o;
    } else if (b < XBLK + WBLK) {
        const float* ws_[6] = {w0, w1, w2, w3, w4, w5};
        int wi = (int)(b - XBLK) >> 4;
        int off = ((int)(b - XBLK) & 15) * 256 + threadIdx.x;  // float4 idx
        float4 v = ((const float4*)ws_[wi])[off];
        ushort4 o = {f2bf(v.x), f2bf(v.y), f2bf(v.z), f2bf(v.w)};
        ((ushort4*)(wb + wi * D * D))[off] = o;
    } else {
        int e = (int)(b - XBLK - WBLK) * 256 + threadIdx.x;
        atomicAdd(&cnt[ei[NE + e]], 1);
    }
}

// ---------------- CSR scan chain ----------------
__global__ __launch_bounds__(256)
void scan_block(const int* __restrict__ cnt, int* __restrict__ row_start,
                int* __restrict__ bsum) {
    __shared__ int tmp[256];
    int i = blockIdx.x * 256 + threadIdx.x;
    int v = (i < NN) ? cnt[i] : 0;
    tmp[threadIdx.x] = v;
    __syncthreads();
    for (int off = 1; off < 256; off <<= 1) {
        int t = (threadIdx.x >= off) ? tmp[threadIdx.x - off] : 0;
        __syncthreads();
        tmp[threadIdx.x] += t;
        __syncthreads();
    }
    if (i < NN) row_start[i] = tmp[threadIdx.x] - v;  // exclusive
    if (threadIdx.x == 255) bsum[blockIdx.x] = tmp[255];
}

__global__ __launch_bounds__(256)
void scan_sums(int* __restrict__ bsum) {
    __shared__ int tmp[256];
    int v = (threadIdx.x < SCAN_BLOCKS) ? bsum[threadIdx.x] : 0;
    tmp[threadIdx.x] = v;
    __syncthreads();
    for (int off = 1; off < 256; off <<= 1) {
        int t = (threadIdx.x >= off) ? tmp[threadIdx.x - off] : 0;
        __syncthreads();
        tmp[threadIdx.x] += t;
        __syncthreads();
    }
    if (threadIdx.x < SCAN_BLOCKS) bsum[threadIdx.x] = tmp[threadIdx.x] - v;
}

__global__ __launch_bounds__(256)
void add_offsets(int* __restrict__ row_start, const int* __restrict__ bsum,
                 int* __restrict__ cursor) {
    int i = blockIdx.x * 256 + threadIdx.x;
    if (i < NN) {
        int v = row_start[i] + bsum[blockIdx.x];
        row_start[i] = v;
        cursor[i] = v;
    } else if (i == NN) {
        row_start[NN] = NE;
    }
}

// ---- fused: gemm (blocks [0,GG)) + CSR fill (blocks [GG,GG+FBLK)) ----
__global__ __launch_bounds__(256)
void gemm_fill(const unsigned short* __restrict__ A,
               const unsigned short* __restrict__ W,
               const float* __restrict__ bias, unsigned short* __restrict__ outp,
               const int* __restrict__ ei, int* __restrict__ cursor,
               unsigned short* __restrict__ src16) {
    if (blockIdx.x >= GG) {
        int e = (int)(blockIdx.x - GG) * 256 + threadIdx.x;
        int src = ei[e];
        int dst = ei[NE + e];
        int pos = atomicAdd(&cursor[dst], 1);
        src16[pos] = (unsigned short)src;
        return;
    }
    const int lane = threadIdx.x & 63;
    const int wave = threadIdx.x >> 6;
    const int quad = lane >> 4;
    const int l16 = lane & 15;
    const int rowBase = blockIdx.x * 64 + wave * 16;

    f32x4 acc[8];
#pragma unroll
    for (int ni = 0; ni < 8; ++ni) acc[ni] = (f32x4){0.f, 0.f, 0.f, 0.f};

    int r = rowBase + l16;
    const int arow = (r < NN ? r : NN - 1) * D;

#pragma unroll
    for (int kt = 0; kt < 4; ++kt) {
        const int ko = kt * 32 + quad * 8;
        bf16x8 a0 = *(const bf16x8*)&A[arow + ko];
#pragma unroll
        for (int ni = 0; ni < 8; ++ni) {
            bf16x8 b = *(const bf16x8*)&W[(ni * 16 + l16) * D + ko];
            acc[ni] = __builtin_amdgcn_mfma_f32_16x16x32_bf16(a0, b, acc[ni], 0, 0, 0);
        }
    }

    float bv[8];
#pragma unroll
    for (int ni = 0; ni < 8; ++ni) bv[ni] = bias[ni * 16 + l16];

#pragma unroll
    for (int rr = 0; rr < 4; ++rr) {
        const int row = rowBase + quad * 4 + rr;
        if (row < NN) {
#pragma unroll
            for (int ni = 0; ni < 8; ++ni) {
                float v = acc[ni][rr] + bv[ni];
                v = v > 0.f ? v : 0.f;
                outp[row * D + (ni * 16 + l16)] = f2bf(v);
            }
        }
    }
}

// ---- plain gemm: out = relu(A@W.T + bias), bf16 out ----
__global__ __launch_bounds__(256)
void gemm_single(const unsigned short* __restrict__ A,
                 const unsigned short* __restrict__ W,
                 const float* __restrict__ bias,
                 unsigned short* __restrict__ outp) {
    const int lane = threadIdx.x & 63;
    const int wave = threadIdx.x >> 6;
    const int quad = lane >> 4;
    const int l16 = lane & 15;
    const int rowBase = blockIdx.x * 64 + wave * 16;

    f32x4 acc[8];
#pragma unroll
    for (int ni = 0; ni < 8; ++ni) acc[ni] = (f32x4){0.f, 0.f, 0.f, 0.f};

    int r = rowBase + l16;
    const int arow = (r < NN ? r : NN - 1) * D;

#pragma unroll
    for (int kt = 0; kt < 4; ++kt) {
        const int ko = kt * 32 + quad * 8;
        bf16x8 a0 = *(const bf16x8*)&A[arow + ko];
#pragma unroll
        for (int ni = 0; ni < 8; ++ni) {
            bf16x8 b = *(const bf16x8*)&W[(ni * 16 + l16) * D + ko];
            acc[ni] = __builtin_amdgcn_mfma_f32_16x16x32_bf16(a0, b, acc[ni], 0, 0, 0);
        }
    }

    float bv[8];
#pragma unroll
    for (int ni = 0; ni < 8; ++ni) bv[ni] = bias[ni * 16 + l16];

#pragma unroll
    for (int rr = 0; rr < 4; ++rr) {
        const int row = rowBase + quad * 4 + rr;
        if (row < NN) {
#pragma unroll
            for (int ni = 0; ni < 8; ++ni) {
                float v = acc[ni][rr] + bv[ni];
                v = v > 0.f ? v : 0.f;
                outp[row * D + (ni * 16 + l16)] = f2bf(v);
            }
        }
    }
}

// ---- quad-split gather-mean: one wave per node ----
// Row = 256 B = 16 lanes x uint4. Quad q handles neighbor (i+q): one load
// instruction fetches 4 neighbor rows; x4 unroll = 16 rows (4 KB) in flight.
// Cross-quad butterfly reduce at the end; quad 0 stores coalesced uint4.
__device__ inline void acc8(float* s, uint4 r) {
    s[0] += bf2f(r.x & 0xffffu); s[1] += bf2f(r.x >> 16);
    s[2] += bf2f(r.y & 0xffffu); s[3] += bf2f(r.y >> 16);
    s[4] += bf2f(r.z & 0xffffu); s[5] += bf2f(r.z >> 16);
    s[6] += bf2f(r.w & 0xffffu); s[7] += bf2f(r.w >> 16);
}

__global__ __launch_bounds__(256)
void gather_mean4(const uint4* __restrict__ P4, const int* __restrict__ row_start,
                  const unsigned short* __restrict__ src16,
                  uint4* __restrict__ agg4) {
    const int n = blockIdx.x * 4 + (threadIdx.x >> 6);
    const int lane = threadIdx.x & 63;
    const int q = lane >> 4;
    const int l16 = lane & 15;
    const int b = row_start[n];
    const int e = row_start[n + 1];

    float s[8];
#pragma unroll
    for (int j = 0; j < 8; ++j) s[j] = 0.f;

    int i = b;
    for (; i + 16 <= e; i += 16) {
        int i0 = src16[i + 0 + q];
        int i1 = src16[i + 4 + q];
        int i2 = src16[i + 8 + q];
        int i3 = src16[i + 12 + q];
        uint4 r0 = P4[i0 * 16 + l16];
        uint4 r1 = P4[i1 * 16 + l16];
        uint4 r2 = P4[i2 * 16 + l16];
        uint4 r3 = P4[i3 * 16 + l16];
        acc8(s, r0); acc8(s, r1); acc8(s, r2); acc8(s, r3);
    }
    for (; i + 4 <= e; i += 4) {
        int i0 = src16[i + q];
        uint4 r0 = P4[i0 * 16 + l16];
        acc8(s, r0);
    }
    const int rem = e - i;
    if (q < rem) {
        int i0 = src16[i + q];
        uint4 r0 = P4[i0 * 16 + l16];
        acc8(s, r0);
    }

#pragma unroll
    for (int j = 0; j < 8; ++j) {
        s[j] += __shfl_xor(s[j], 16);
        s[j] += __shfl_xor(s[j], 32);
    }

    const int deg = e - b;
    const float inv = 1.0f / (float)(deg > 0 ? deg : 1);
    if (q == 0) {
        uint4 o;
        o.x = (unsigned)f2bf(s[0] * inv) | ((unsigned)f2bf(s[1] * inv) << 16);
        o.y = (unsigned)f2bf(s[2] * inv) | ((unsigned)f2bf(s[3] * inv) << 16);
        o.z = (unsigned)f2bf(s[4] * inv) | ((unsigned)f2bf(s[5] * inv) << 16);
        o.w = (unsigned)f2bf(s[6] * inv) | ((unsigned)f2bf(s[7] * inv) << 16);
        agg4[n * 16 + l16] = o;
    }
}

// ---- dual gemm: out = A1@W1.T + A2@W2.T + bias, opt relu ----
template <typename OUTT>
__global__ __launch_bounds__(256)
void gemm_dual(const unsigned short* __restrict__ A1,
               const unsigned short* __restrict__ W1,
               const unsigned short* __restrict__ A2,
               const unsigned short* __restrict__ W2,
               const float* __restrict__ bias, OUTT* __restrict__ out,
               int do_relu) {
    const int lane = threadIdx.x & 63;
    const int wave = threadIdx.x >> 6;
    const int quad = lane >> 4;
    const int l16 = lane & 15;
    const int rowBase = blockIdx.x * 64 + wave * 16;

    f32x4 acc[8];
#pragma unroll
    for (int ni = 0; ni < 8; ++ni) acc[ni] = (f32x4){0.f, 0.f, 0.f, 0.f};

    int r = rowBase + l16;
    const int arow = (r < NN ? r : NN - 1) * D;

#pragma unroll
    for (int kt = 0; kt < 4; ++kt) {
        const int ko = kt * 32 + quad * 8;
        bf16x8 a1 = *(const bf16x8*)&A1[arow + ko];
        bf16x8 a2 = *(const bf16x8*)&A2[arow + ko];
#pragma unroll
        for (int ni = 0; ni < 8; ++ni) {
            bf16x8 b1 = *(const bf16x8*)&W1[(ni * 16 + l16) * D + ko];
            bf16x8 b2 = *(const bf16x8*)&W2[(ni * 16 + l16) * D + ko];
            acc[ni] = __builtin_amdgcn_mfma_f32_16x16x32_bf16(a1, b1, acc[ni], 0, 0, 0);
            acc[ni] = __builtin_amdgcn_mfma_f32_16x16x32_bf16(a2, b2, acc[ni], 0, 0, 0);
        }
    }

    float bv[8];
#pragma unroll
    for (int ni = 0; ni < 8; ++ni) bv[ni] = bias[ni * 16 + l16];

#pragma unroll
    for (int rr = 0; rr < 4; ++rr) {
        const int row = rowBase + quad * 4 + rr;
        if (row < NN) {
#pragma unroll
            for (int ni = 0; ni < 8; ++ni) {
                float v = acc[ni][rr] + bv[ni];
                if (do_relu) v = v > 0.f ? v : 0.f;
                const int c = ni * 16 + l16;
                if constexpr (sizeof(OUTT) == 2)
                    out[row * D + c] = (OUTT)f2bf(v);
                else
                    out[row * D + c] = (OUTT)v;
            }
        }
    }
}

extern "C" void kernel_launch(void* const* d_in, const int* in_sizes, int n_in,
                              void* d_out, int out_size, void* d_ws, size_t ws_size,
                              hipStream_t stream) {
    const float* x   = (const float*)d_in[0];
    const int*   ei  = (const int*)d_in[1];
    const float* Wp1 = (const float*)d_in[2];
    const float* bp1 = (const float*)d_in[3];
    const float* Wl1 = (const float*)d_in[4];
    const float* bl1 = (const float*)d_in[5];
    const float* Wr1 = (const float*)d_in[6];
    const float* Wp2 = (const float*)d_in[7];
    const float* bp2 = (const float*)d_in[8];
    const float* Wl2 = (const float*)d_in[9];
    const float* bl2 = (const float*)d_in[10];
    const float* Wr2 = (const float*)d_in[11];
    float* out = (float*)d_out;

    char* ws = (char*)d_ws;
    size_t off = 0;
    auto alloc = [&](size_t bytes) {
        void* p = ws + off;
        off += (bytes + 511) & ~511ull;
        return p;
    };
    unsigned short* Wb   = (unsigned short*)alloc((size_t)6 * D * D * 2);
    unsigned short* xb   = (unsigned short*)alloc((size_t)NN * D * 2);
    unsigned short* bufP = (unsigned short*)alloc((size_t)NN * D * 2);  // projected
    unsigned short* bufAg= (unsigned short*)alloc((size_t)NN * D * 2);  // aggregated
    unsigned short* bufH = (unsigned short*)alloc((size_t)NN * D * 2);  // layer-1 out
    int* cnt        = (int*)alloc((size_t)NN * 4);
    int* row_start  = (int*)alloc((size_t)(NN + 1) * 4);
    int* cursor     = (int*)alloc((size_t)NN * 4);
    int* bsum       = (int*)alloc((size_t)SCAN_BLOCKS * 4);
    unsigned short* src16 = (unsigned short*)alloc((size_t)NE * 2);

    // 1. conversions + degree histogram (one dispatch)
    hipMemsetAsync(cnt, 0, (size_t)NN * 4, stream);
    prep<<<XBLK + WBLK + HBLK, 256, 0, stream>>>(
        x, Wp1, Wl1, Wr1, Wp2, Wl2, Wr2, ei, xb, Wb, cnt);

    // 2. scan chain
    scan_block<<<SCAN_BLOCKS, 256, 0, stream>>>(cnt, row_start, bsum);
    scan_sums<<<1, 256, 0, stream>>>(bsum);
    add_offsets<<<SCAN_BLOCKS, 256, 0, stream>>>(row_start, bsum, cursor);

    // 3. layer-1 projection gemm fused with CSR fill
    gemm_fill<<<GG + FBLK, 256, 0, stream>>>(
        xb, Wb + 0 * D * D, bp1, bufP, ei, cursor, src16);

    const int GA = NN / 4;  // 12500 gather blocks

    // 4. layer-1 aggregate + combine
    gather_mean4<<<GA, 256, 0, stream>>>(
        (const uint4*)bufP, row_start, src16, (uint4*)bufAg);
    gemm_dual<unsigned short><<<GG, 256, 0, stream>>>(
        bufAg, Wb + 1 * D * D, xb, Wb + 2 * D * D, bl1, bufH, 1);

    // 5. layer-2 projection
    gemm_single<<<GG, 256, 0, stream>>>(bufH, Wb + 3 * D * D, bp2, bufP);

    // 6. layer-2 aggregate + combine (f32 out)
    gather_mean4<<<GA, 256, 0, stream>>>(
        (const uint4*)bufP, row_start, src16, (uint4*)bufAg);
    gemm_dual<float><<<GG, 256, 0, stream>>>(
        bufAg, Wb + 4 * D * D, bufH, Wb + 5 * D * D, bl2, out, 0);
}